// Round 1
// baseline (240.402 us; speedup 1.0000x reference)
//
#include <hip/hip_runtime.h>

// InverseBarkScale: 30-iter SGD with momentum inverting a bark filterbank.
// Key fact: fb (513x128) has <=2 nonzeros per freq row (triangular filters),
// and each bark column's support is a contiguous freq interval. So both
// einsums are sparse: ~1026 MACs per row per direction instead of 65664.
//
// Pipeline (all on stream, graph-capture safe):
//   1. setup_kernel: extract sparse structure of fb into d_ws
//   2. iter_kernel(mode=0): all rows run 30 iters speculatively (no global
//      sync), write deterministic per-block per-iter loss partials + output
//   3. scan_kernel: reduce partials -> loss[30], simulate reference stop
//      logic -> S (iterations actually applied)
//   4. iter_kernel(mode=1): if S==30 exit immediately (expected path);
//      else re-run with exactly S iterations and overwrite output.

#define NSTFT 513
#define NBARK 128
#define BATCH 4
#define TIME  512
#define MAXIT 30
#define NROWS (BATCH*TIME)   // 2048 independent rows, 1 wave each
#define NBLK  (NROWS/4)      // 512 blocks of 4 waves

// d_ws layout (bytes); ~71 KB total. Re-poisoned each call; every field is
// written by our kernels before being read in the same call.
#define WS_S_OFF  0                        // int: stop iteration S
#define WS_BP_OFF 16                       // float[MAXIT][NBLK] loss partials
#define WS_FT_OFF (16 + 4*MAXIT*NBLK)      // float4[NSTFT]: {k1,w1,k2,w2}/freq
#define WS_FS_OFF (WS_FT_OFF + 16*NSTFT)   // int[NBARK]: column support start
#define WS_NN_OFF (WS_FS_OFF + 4*NBARK)    // int[NBARK]: column support length

#define SPEC_STRIDE 516

__global__ __launch_bounds__(128) void setup_kernel(const float* __restrict__ fb,
                                                    char* __restrict__ ws) {
    int gid = blockIdx.x * blockDim.x + threadIdx.x;
    float4* ftab = (float4*)(ws + WS_FT_OFF);
    int* fstart  = (int*)(ws + WS_FS_OFF);
    int* nnzp    = (int*)(ws + WS_NN_OFF);
    if (gid < NSTFT) {
        int f = gid;
        int k1 = 0, k2 = 0, c = 0;
        float w1 = 0.f, w2 = 0.f;
        for (int k = 0; k < NBARK; ++k) {
            float w = fb[f*NBARK + k];
            if (w > 0.f) {
                if (c == 0)      { k1 = k; w1 = w; }
                else if (c == 1) { k2 = k; w2 = w; }
                ++c;
            }
        }
        if (c < 2) { k2 = k1; w2 = 0.f; }   // rows with 0/1 nonzeros
        float4 e;
        e.x = __int_as_float(k1); e.y = w1;
        e.z = __int_as_float(k2); e.w = w2;
        ftab[f] = e;
    } else if (gid < NSTFT + NBARK) {
        int k = gid - NSTFT;
        int fs = 0, n = 0;
        for (int f = 0; f < NSTFT; ++f) {
            float w = fb[f*NBARK + k];
            if (w > 0.f) { if (n == 0) fs = f; ++n; }   // contiguous support
        }
        fstart[k] = fs; nnzp[k] = n;
    }
}

__global__ __launch_bounds__(256) void
iter_kernel(const float* __restrict__ barkspec,
            const float* __restrict__ spec_init,
            float* __restrict__ out,
            char* __restrict__ ws, int mode)
{
    __shared__ float  sspec[4][SPEC_STRIDE];  // per-row spec (gather target)
    __shared__ float  sdiff[4][NBARK];        // per-row residual
    __shared__ float4 sftab[NSTFT];           // {k1,w1,k2,w2} per freq
    __shared__ int    sfs[NBARK];
    __shared__ int    snn[NBARK];
    __shared__ float  wpart[4];

    const int tid  = threadIdx.x;
    const int wave = tid >> 6, lane = tid & 63;

    int niter = MAXIT;
    if (mode) {
        int S = *(const volatile int*)(ws + WS_S_OFF);
        if (S >= MAXIT) return;              // expected path: no repair needed
        niter = S;
    }

    // Stage sparse tables to LDS (coalesced; shared by the 4 rows).
    const float4* gft = (const float4*)(ws + WS_FT_OFF);
    for (int i = tid; i < NSTFT; i += 256) sftab[i] = gft[i];
    if (tid < NBARK) {
        sfs[tid] = ((const int*)(ws + WS_FS_OFF))[tid];
        snn[tid] = ((const int*)(ws + WS_NN_OFF))[tid];
    }

    const int r     = blockIdx.x * 4 + wave;  // row = (batch, t)
    const int batch = r >> 9;
    const int t     = r & (TIME - 1);

    // Each lane owns bark columns {lane, lane+64} (interleaved for balance:
    // column widths grow with k) and freq slices f = lane + 64*s.
    const int c0 = lane, c1 = lane + 64;
    const float* bs = barkspec + (size_t)batch*NBARK*TIME + t;
    const float m0 = bs[c0*TIME];
    const float m1 = bs[c1*TIME];

    const float* sp = spec_init + ((size_t)batch*TIME + t)*NSTFT;
    float buf[9];   // momentum buffer lives in registers
#pragma unroll
    for (int s = 0; s < 9; ++s) {
        int f = lane + 64*s;
        if (f < NSTFT) sspec[wave][f] = sp[f];
        buf[s] = 0.f;
    }
    __syncthreads();

    float* bp = (float*)(ws + WS_BP_OFF);
    const float GC = -2.0f / (float)NROWS;    // -2 * inv_n

    for (int it = 0; it < niter; ++it) {
        // ---- forward: diff[k] = m[k] - sum_{f in supp(k)} spec[f]*fb[f,k]
        float lp = 0.f;
        {
            float acc = 0.f;
            const int fs = sfs[c0], n = snn[c0];
            for (int i = 0; i < n; ++i) {
                int f = fs + i;
                float4 e = sftab[f];
                float w = (__float_as_int(e.x) == c0) ? e.y : e.w;
                acc = fmaf(sspec[wave][f], w, acc);
            }
            float d = m0 - acc;
            sdiff[wave][c0] = d;
            lp = fmaf(d, d, lp);
        }
        {
            float acc = 0.f;
            const int fs = sfs[c1], n = snn[c1];
            for (int i = 0; i < n; ++i) {
                int f = fs + i;
                float4 e = sftab[f];
                float w = (__float_as_int(e.x) == c1) ? e.y : e.w;
                acc = fmaf(sspec[wave][f], w, acc);
            }
            float d = m1 - acc;
            sdiff[wave][c1] = d;
            lp = fmaf(d, d, lp);
        }
        if (!mode) {
            // deterministic wave reduction (butterfly)
            for (int msk = 32; msk; msk >>= 1) lp += __shfl_xor(lp, msk);
            if (lane == 0) wpart[wave] = lp;
        }
        __syncthreads();   // diff + wpart visible
        if (!mode && tid == 0)
            bp[it*NBLK + blockIdx.x] = wpart[0]+wpart[1]+wpart[2]+wpart[3];

        // ---- backward + SGD update: grad[f] = GC*(d[k1]*w1 + d[k2]*w2)
#pragma unroll
        for (int s = 0; s < 9; ++s) {
            int f = lane + 64*s;
            if (f < NSTFT) {
                float4 e = sftab[f];
                int k1 = __float_as_int(e.x);
                int k2 = __float_as_int(e.z);
                float g  = GC * (sdiff[wave][k1]*e.y + sdiff[wave][k2]*e.w);
                float b2 = fmaf(0.9f, buf[s], g);
                buf[s] = b2;
                float v = sspec[wave][f] - 0.1f*b2;
                sspec[wave][f] = v < 0.f ? 0.f : v;
            }
        }
        __syncthreads();   // spec update visible before next forward
    }

    // ---- transposed store: out[batch, f, t0..t0+3] as float4
    const int t0 = (blockIdx.x * 4) & (TIME - 1);
    float4* og = (float4*)out;
    for (int f = tid; f < NSTFT; f += 256) {
        float4 v;
        v.x = sspec[0][f]; v.y = sspec[1][f];
        v.z = sspec[2][f]; v.w = sspec[3][f];
        og[((size_t)batch*NSTFT + f)*(TIME/4) + (t0 >> 2)] = v;
    }
}

__global__ __launch_bounds__(256) void scan_kernel(char* __restrict__ ws) {
    __shared__ float red[256];
    __shared__ float losses[MAXIT];
    const int tid = threadIdx.x;
    const float* bp = (const float*)(ws + WS_BP_OFF);
    for (int it = 0; it < MAXIT; ++it) {
        float s = bp[it*NBLK + tid] + bp[it*NBLK + tid + 256];
        red[tid] = s;
        __syncthreads();
        for (int h = 128; h; h >>= 1) {
            if (tid < h) red[tid] += red[tid + h];
            __syncthreads();
        }
        if (tid == 0) losses[it] = red[0] * (1.0f/(float)NROWS);
        __syncthreads();
    }
    if (tid == 0) {
        // reference stop logic: update is applied on the stop iteration,
        // frozen afterwards -> S = first stop index + 1, else MAXIT
        float prev = __builtin_inff();
        int S = MAXIT;
        for (int i = 0; i < MAXIT; ++i) {
            float l = losses[i];
            if (l < 1e-5f || fabsf(prev - l) < 1e-8f) { S = i + 1; break; }
            prev = l;
        }
        *(int*)(ws + WS_S_OFF) = S;
    }
}

extern "C" void kernel_launch(void* const* d_in, const int* in_sizes, int n_in,
                              void* d_out, int out_size, void* d_ws, size_t ws_size,
                              hipStream_t stream)
{
    const float* barkspec  = (const float*)d_in[0];
    const float* fb        = (const float*)d_in[1];
    const float* spec_init = (const float*)d_in[2];
    float* out = (float*)d_out;
    char* ws = (char*)d_ws;

    setup_kernel<<<6, 128, 0, stream>>>(fb, ws);
    iter_kernel<<<NBLK, 256, 0, stream>>>(barkspec, spec_init, out, ws, 0);
    scan_kernel<<<1, 256, 0, stream>>>(ws);
    iter_kernel<<<NBLK, 256, 0, stream>>>(barkspec, spec_init, out, ws, 1);
}